// Round 1
// baseline (327.928 us; speedup 1.0000x reference)
//
#include <hip/hip_runtime.h>
#include <hip/hip_bf16.h>

#define B_  32
#define C_  128
#define T_  8192
#define K_  5
#define MC  256          // M*C = fc1 outputs
#define WPB 81920        // per-sample weight elements: 128*5*128

typedef short bf16x8 __attribute__((ext_vector_type(8)));
typedef float f32x4  __attribute__((ext_vector_type(4)));

static __device__ __forceinline__ unsigned short f2bf(float f) {
    // RNE round to bf16 (values are tame: no NaN/Inf in this problem)
    unsigned int u = __float_as_uint(f);
    u += 0x7FFFu + ((u >> 16) & 1u);
    return (unsigned short)(u >> 16);
}

// ---------------- kernel 1: masked GAP  (B*C blocks) ----------------
__global__ __launch_bounds__(256) void gap_kernel(const float* __restrict__ x,
                                                  const int* __restrict__ len,
                                                  float* __restrict__ gap) {
    const int row = blockIdx.x;                 // b*128 + c
    const float* xr = x + (size_t)row * T_;
    const int tid = threadIdx.x;
    float s = 0.f;
    const float4* xv = reinterpret_cast<const float4*>(xr);
#pragma unroll
    for (int i = 0; i < T_ / 4 / 256; ++i) {
        float4 v = xv[tid + i * 256];
        s += v.x + v.y + v.z + v.w;
    }
#pragma unroll
    for (int off = 32; off; off >>= 1) s += __shfl_down(s, off);
    __shared__ float red[4];
    if ((tid & 63) == 0) red[tid >> 6] = s;
    __syncthreads();
    if (tid == 0) {
        float tot = red[0] + red[1] + red[2] + red[3];
        gap[row] = tot / (float)len[row >> 7];
    }
}

// ---------------- kernel 2: fc1 + sigmoid  (B blocks) ----------------
__global__ __launch_bounds__(256) void fc1_kernel(const float* __restrict__ gap,
                                                  const float* __restrict__ w1,
                                                  const float* __restrict__ b1,
                                                  float* __restrict__ h) {
    const int b = blockIdx.x;
    const int o = threadIdx.x;                  // 0..255
    __shared__ float g[C_];
    if (o < C_) g[o] = gap[b * C_ + o];
    __syncthreads();
    float acc = b1[o];
    const float* wr = w1 + o * C_;
#pragma unroll 8
    for (int c = 0; c < C_; ++c) acc += g[c] * wr[c];
    h[b * MC + o] = 1.f / (1.f + expf(-acc));
}

// ------------- kernel 3: dynamic weights, layout [b][co][k][ci] bf16 -------------
__global__ __launch_bounds__(256) void wgen_kernel(const float* __restrict__ h,
                                                   const float* __restrict__ w2,
                                                   unsigned short* __restrict__ W) {
    const int idx = blockIdx.x * 256 + threadIdx.x;   // 32*128*5*128 = 2,621,440
    const int ci = idx & 127;
    const int t1 = idx >> 7;          // (b*128+co)*5 + k
    const int k  = t1 % 5;
    const int t2 = t1 / 5;            // b*128 + co
    const int co = t2 & 127;
    const int b  = t2 >> 7;
    // group index g = (co*640 + ci*5 + k) / 320 = 2*co + (ci >= 64)
    const float hv = h[b * MC + 2 * co + (ci >= 64)];
    const float wv = w2[co * 640 + ci * 5 + k];
    W[idx] = f2bf(hv * wv);
}

// ---------------- kernel 4: dynamic conv via MFMA ----------------
// grid (T/128, B), 256 threads = 4 waves. Each block: 128 co x 128 t.
// LDS x tile transposed: xs[trow][ci], trow 0..135 <-> t = t0-4+trow,
// row stride 136 (128 + 8 pad) ushorts = 272 B (16B-aligned rows, bank spread 4).
__global__ __launch_bounds__(256) void conv_kernel(const float* __restrict__ x,
                                                   const unsigned short* __restrict__ W,
                                                   float* __restrict__ out) {
    const int t0 = blockIdx.x * 128;
    const int b  = blockIdx.y;
    const int tid = threadIdx.x;

    __shared__ unsigned short xs[136 * 136];

    // ---- stage x tile (fp32 -> bf16, transpose) ----
    const float* xb = x + (size_t)b * C_ * T_;
#pragma unroll
    for (int it = 0; it < 17; ++it) {
        int i  = tid + it * 256;          // 0..4351 over 32 cg x 136 tl
        int cg = i / 136;                 // ci group of 4
        int tl = i - cg * 136;
        int t  = t0 - 4 + tl;
        float v0 = 0.f, v1 = 0.f, v2 = 0.f, v3 = 0.f;
        if (t >= 0 && t < T_) {
            const float* p = xb + (size_t)(4 * cg) * T_ + t;
            v0 = p[0]; v1 = p[T_]; v2 = p[2 * T_]; v3 = p[3 * T_];
        }
        ushort4 pk;
        pk.x = f2bf(v0); pk.y = f2bf(v1); pk.z = f2bf(v2); pk.w = f2bf(v3);
        *reinterpret_cast<ushort4*>(&xs[tl * 136 + 4 * cg]) = pk;  // ds_write_b64
    }
    __syncthreads();

    const int w  = tid >> 6;
    const int l  = tid & 63;
    const int wr = w >> 1, wc = w & 1;    // wave quadrant: rows (co), cols (t)
    const int lr = l & 15, lh = l >> 4;

    f32x4 acc[4][4];
#pragma unroll
    for (int mt = 0; mt < 4; ++mt)
#pragma unroll
        for (int nt = 0; nt < 4; ++nt)
#pragma unroll
            for (int r = 0; r < 4; ++r) acc[mt][nt][r] = 0.f;

    const unsigned short* Wb = W + (size_t)b * WPB;

#pragma unroll
    for (int k = 0; k < K_; ++k) {
#pragma unroll
        for (int kc = 0; kc < 4; ++kc) {
            bf16x8 Af[4], Bf[4];
#pragma unroll
            for (int mt = 0; mt < 4; ++mt) {
                int co = wr * 64 + mt * 16 + lr;
                Af[mt] = *reinterpret_cast<const bf16x8*>(
                    Wb + co * 640 + k * 128 + kc * 32 + 8 * lh);
            }
#pragma unroll
            for (int nt = 0; nt < 4; ++nt) {
                int row = wc * 64 + nt * 16 + lr + k + 2;   // t index in xs
                Bf[nt] = *reinterpret_cast<const bf16x8*>(
                    &xs[row * 136 + kc * 32 + 8 * lh]);     // ds_read_b128
            }
#pragma unroll
            for (int mt = 0; mt < 4; ++mt)
#pragma unroll
                for (int nt = 0; nt < 4; ++nt)
                    acc[mt][nt] = __builtin_amdgcn_mfma_f32_16x16x32_bf16(
                        Af[mt], Bf[nt], acc[mt][nt], 0, 0, 0);
        }
    }

    // ---- epilogue: D[row=4*lh+r][col=lr] ----
    float* ob = out + (size_t)b * C_ * T_;
#pragma unroll
    for (int mt = 0; mt < 4; ++mt) {
#pragma unroll
        for (int nt = 0; nt < 4; ++nt) {
            int tcol = t0 + wc * 64 + nt * 16 + lr;
#pragma unroll
            for (int r = 0; r < 4; ++r) {
                int co = wr * 64 + mt * 16 + lh * 4 + r;
                ob[(size_t)co * T_ + tcol] = acc[mt][nt][r];
            }
        }
    }
}

extern "C" void kernel_launch(void* const* d_in, const int* in_sizes, int n_in,
                              void* d_out, int out_size, void* d_ws, size_t ws_size,
                              hipStream_t stream) {
    const float* x   = (const float*)d_in[0];
    const int*   len = (const int*)d_in[1];
    const float* w1  = (const float*)d_in[2];
    const float* b1  = (const float*)d_in[3];
    const float* w2  = (const float*)d_in[4];
    float* out = (float*)d_out;

    char* ws = (char*)d_ws;
    float* gap = (float*)ws;                              // 16 KB
    float* h   = (float*)(ws + 16384);                    // 32 KB
    unsigned short* W = (unsigned short*)(ws + 65536);    // 5.24 MB

    gap_kernel<<<B_ * C_, 256, 0, stream>>>(x, len, gap);
    fc1_kernel<<<B_, 256, 0, stream>>>(gap, w1, b1, h);
    wgen_kernel<<<(B_ * WPB) / 256, 256, 0, stream>>>(h, w2, W);
    dim3 g(T_ / 128, B_);
    conv_kernel<<<g, 256, 0, stream>>>(x, W, out);
}

// Round 2
// 323.998 us; speedup vs baseline: 1.0121x; 1.0121x over previous
//
#include <hip/hip_runtime.h>
#include <hip/hip_bf16.h>

#define B_  32
#define C_  128
#define T_  8192
#define K_  5
#define MC  256          // M*C = fc1 outputs
#define WPB 81920        // per-sample weight elements: 128*5*128

typedef short bf16x8 __attribute__((ext_vector_type(8)));
typedef float f32x4  __attribute__((ext_vector_type(4)));

static __device__ __forceinline__ unsigned short f2bf(float f) {
    // RNE round to bf16 (values are tame: no NaN/Inf in this problem)
    unsigned int u = __float_as_uint(f);
    u += 0x7FFFu + ((u >> 16) & 1u);
    return (unsigned short)(u >> 16);
}

// ---------------- kernel 1: masked GAP  (B*C blocks) ----------------
__global__ __launch_bounds__(256) void gap_kernel(const float* __restrict__ x,
                                                  const int* __restrict__ len,
                                                  float* __restrict__ gap) {
    const int row = blockIdx.x;                 // b*128 + c
    const float* xr = x + (size_t)row * T_;
    const int tid = threadIdx.x;
    float s = 0.f;
    const float4* xv = reinterpret_cast<const float4*>(xr);
#pragma unroll
    for (int i = 0; i < T_ / 4 / 256; ++i) {
        float4 v = xv[tid + i * 256];
        s += v.x + v.y + v.z + v.w;
    }
#pragma unroll
    for (int off = 32; off; off >>= 1) s += __shfl_down(s, off);
    __shared__ float red[4];
    if ((tid & 63) == 0) red[tid >> 6] = s;
    __syncthreads();
    if (tid == 0) {
        float tot = red[0] + red[1] + red[2] + red[3];
        gap[row] = tot / (float)len[row >> 7];
    }
}

// ---------------- kernel 2: fc1 + sigmoid  (B blocks) ----------------
__global__ __launch_bounds__(256) void fc1_kernel(const float* __restrict__ gap,
                                                  const float* __restrict__ w1,
                                                  const float* __restrict__ b1,
                                                  float* __restrict__ h) {
    const int b = blockIdx.x;
    const int o = threadIdx.x;                  // 0..255
    __shared__ float g[C_];
    if (o < C_) g[o] = gap[b * C_ + o];
    __syncthreads();
    float acc = b1[o];
    const float* wr = w1 + o * C_;
#pragma unroll 8
    for (int c = 0; c < C_; ++c) acc += g[c] * wr[c];
    h[b * MC + o] = 1.f / (1.f + expf(-acc));
}

// ------------- kernel 3: dynamic weights, layout [b][co][k][ci] bf16 -------------
__global__ __launch_bounds__(256) void wgen_kernel(const float* __restrict__ h,
                                                   const float* __restrict__ w2,
                                                   unsigned short* __restrict__ W) {
    const int idx = blockIdx.x * 256 + threadIdx.x;   // 32*128*5*128 = 2,621,440
    const int ci = idx & 127;
    const int t1 = idx >> 7;          // (b*128+co)*5 + k
    const int k  = t1 % 5;
    const int t2 = t1 / 5;            // b*128 + co
    const int co = t2 & 127;
    const int b  = t2 >> 7;
    // group index g = (co*640 + ci*5 + k) / 320 = 2*co + (ci >= 64)
    const float hv = h[b * MC + 2 * co + (ci >= 64)];
    const float wv = w2[co * 640 + ci * 5 + k];
    W[idx] = f2bf(hv * wv);
}

// ---------------- kernel 4: dynamic conv via MFMA ----------------
// grid (T/128, B), 256 threads = 4 waves. Each block: 128 co x 128 t.
// LDS x tile transposed: xs[trow][ci], trow 0..135 <-> t = t0-4+trow,
// row stride 136 (128 + 8 pad) ushorts = 272 B (16B-aligned rows, bank spread 4).
// Staging: all 68 global loads hoisted into regs in 2 batches (~2 HBM
// round-trips instead of 17). __launch_bounds__(256,4): LDS already caps at
// 4 blocks/CU, so allow the compiler up to 128 VGPRs.
__global__ __launch_bounds__(256, 4) void conv_kernel(const float* __restrict__ x,
                                                      const unsigned short* __restrict__ W,
                                                      float* __restrict__ out) {
    const int t0 = blockIdx.x * 128;
    const int b  = blockIdx.y;
    const int tid = threadIdx.x;

    __shared__ unsigned short xs[136 * 136];

    const float* xb = x + (size_t)b * C_ * T_;

    // ---- stage x tile (fp32 -> bf16, transpose), batched loads ----
    float4 va[9], vb[8];
#pragma unroll
    for (int it = 0; it < 9; ++it) {
        int i  = tid + it * 256;          // over 32 cg x 136 tl
        int cg = i / 136;
        int tl = i - cg * 136;
        int t  = t0 - 4 + tl;
        float4 v = {0.f, 0.f, 0.f, 0.f};
        if (t >= 0 && t < T_) {
            const float* p = xb + (size_t)(4 * cg) * T_ + t;
            v.x = p[0]; v.y = p[T_]; v.z = p[2 * T_]; v.w = p[3 * T_];
        }
        va[it] = v;
    }
#pragma unroll
    for (int it = 0; it < 8; ++it) {
        int i  = tid + (9 + it) * 256;
        int cg = i / 136;
        int tl = i - cg * 136;
        int t  = t0 - 4 + tl;
        float4 v = {0.f, 0.f, 0.f, 0.f};
        if (t >= 0 && t < T_) {
            const float* p = xb + (size_t)(4 * cg) * T_ + t;
            v.x = p[0]; v.y = p[T_]; v.z = p[2 * T_]; v.w = p[3 * T_];
        }
        vb[it] = v;
    }
#pragma unroll
    for (int it = 0; it < 9; ++it) {
        int i  = tid + it * 256;
        int cg = i / 136;
        int tl = i - cg * 136;
        ushort4 pk;
        pk.x = f2bf(va[it].x); pk.y = f2bf(va[it].y);
        pk.z = f2bf(va[it].z); pk.w = f2bf(va[it].w);
        *reinterpret_cast<ushort4*>(&xs[tl * 136 + 4 * cg]) = pk;
    }
#pragma unroll
    for (int it = 0; it < 8; ++it) {
        int i  = tid + (9 + it) * 256;
        int cg = i / 136;
        int tl = i - cg * 136;
        ushort4 pk;
        pk.x = f2bf(vb[it].x); pk.y = f2bf(vb[it].y);
        pk.z = f2bf(vb[it].z); pk.w = f2bf(vb[it].w);
        *reinterpret_cast<ushort4*>(&xs[tl * 136 + 4 * cg]) = pk;
    }
    __syncthreads();

    const int w  = tid >> 6;
    const int l  = tid & 63;
    const int wr = w >> 1, wc = w & 1;    // wave quadrant: rows (co), cols (t)
    const int lr = l & 15, lh = l >> 4;

    f32x4 acc[4][4];
#pragma unroll
    for (int mt = 0; mt < 4; ++mt)
#pragma unroll
        for (int nt = 0; nt < 4; ++nt)
#pragma unroll
            for (int r = 0; r < 4; ++r) acc[mt][nt][r] = 0.f;

    const unsigned short* Wb = W + (size_t)b * WPB;

#pragma unroll
    for (int k = 0; k < K_; ++k) {
#pragma unroll
        for (int kc = 0; kc < 4; ++kc) {
            bf16x8 Af[4], Bf[4];
#pragma unroll
            for (int mt = 0; mt < 4; ++mt) {
                int co = wr * 64 + mt * 16 + lr;
                Af[mt] = *reinterpret_cast<const bf16x8*>(
                    Wb + co * 640 + k * 128 + kc * 32 + 8 * lh);
            }
#pragma unroll
            for (int nt = 0; nt < 4; ++nt) {
                int row = wc * 64 + nt * 16 + lr + k + 2;   // t index in xs
                Bf[nt] = *reinterpret_cast<const bf16x8*>(
                    &xs[row * 136 + kc * 32 + 8 * lh]);     // ds_read_b128
            }
#pragma unroll
            for (int mt = 0; mt < 4; ++mt)
#pragma unroll
                for (int nt = 0; nt < 4; ++nt)
                    acc[mt][nt] = __builtin_amdgcn_mfma_f32_16x16x32_bf16(
                        Af[mt], Bf[nt], acc[mt][nt], 0, 0, 0);
        }
    }

    // ---- epilogue: D[row=4*lh+r][col=lr] ----
    float* ob = out + (size_t)b * C_ * T_;
#pragma unroll
    for (int mt = 0; mt < 4; ++mt) {
#pragma unroll
        for (int nt = 0; nt < 4; ++nt) {
            int tcol = t0 + wc * 64 + nt * 16 + lr;
#pragma unroll
            for (int r = 0; r < 4; ++r) {
                int co = wr * 64 + mt * 16 + lh * 4 + r;
                ob[(size_t)co * T_ + tcol] = acc[mt][nt][r];
            }
        }
    }
}

extern "C" void kernel_launch(void* const* d_in, const int* in_sizes, int n_in,
                              void* d_out, int out_size, void* d_ws, size_t ws_size,
                              hipStream_t stream) {
    const float* x   = (const float*)d_in[0];
    const int*   len = (const int*)d_in[1];
    const float* w1  = (const float*)d_in[2];
    const float* b1  = (const float*)d_in[3];
    const float* w2  = (const float*)d_in[4];
    float* out = (float*)d_out;

    char* ws = (char*)d_ws;
    float* gap = (float*)ws;                              // 16 KB
    float* h   = (float*)(ws + 16384);                    // 32 KB
    unsigned short* W = (unsigned short*)(ws + 65536);    // 5.24 MB

    gap_kernel<<<B_ * C_, 256, 0, stream>>>(x, len, gap);
    fc1_kernel<<<B_, 256, 0, stream>>>(gap, w1, b1, h);
    wgen_kernel<<<(B_ * WPB) / 256, 256, 0, stream>>>(h, w2, W);
    dim3 g(T_ / 128, B_);
    conv_kernel<<<g, 256, 0, stream>>>(x, W, out);
}